// Round 13
// baseline (500.749 us; speedup 1.0000x reference)
//
#include <hip/hip_runtime.h>
#include <hip/hip_bf16.h>
#include <math.h>

#define TOK   4096
#define DIM   1024
#define DMLP  4096
#define NE    8
#define BM    128
#define BN2   64
#define PADMAX (TOK + NE * BM)   // 5120 padded slots
#define NTILES (PADMAX / BM)     // 40 row-tiles
#define MAXSUP 24                // max 256-row supertiles
#define NT1   16                 // gemm1 K-tiles (1024/64)

typedef __attribute__((ext_vector_type(8))) short  short8;
typedef __attribute__((ext_vector_type(4))) float  float4v;
typedef __attribute__((ext_vector_type(4))) unsigned short ushort4v;
typedef __attribute__((ext_vector_type(2))) unsigned long long ull2;

// async global->LDS, 16 B per lane; LDS dest is wave-uniform base + lane*16
#define ASYNC16(gp, lp) __builtin_amdgcn_global_load_lds( \
    (const __attribute__((address_space(1))) unsigned int*)(gp), \
    (__attribute__((address_space(3))) unsigned int*)(lp), 16, 0, 0)

// BK=64 A-side swizzle (8 granules/row, involution) - gemm1 halves
#define FRAG_OFF64(R, C) ((((R) << 3) + ((C) ^ ((R) & 7))) << 3)
// BK=128 A-side swizzle (16 granules/row) - gemm2 (r9 proven)
#define SWZ128(R, C) (((C) & 8) | (((C) ^ (R)) & 7))
#define FRAG_OFF128(R, C) ((((R) << 4) + SWZ128(R, C)) << 3)

static __device__ __forceinline__ unsigned short f2bf(float f) {
  unsigned u = __float_as_uint(f);
  u += 0x7fffu + ((u >> 16) & 1u);
  return (unsigned short)(u >> 16);
}

// exact-erf GELU via Abramowitz&Stegun 7.1.26 (|err| < 1.5e-7)
static __device__ __forceinline__ float gelu_erf(float v) {
  const float x = fabsf(v) * 0.70710678118654752f;
  const float t = __builtin_amdgcn_rcpf(1.0f + 0.3275911f * x);
  const float poly = ((((1.061405429f * t - 1.453152027f) * t + 1.421413741f) * t
                       - 0.284496736f) * t + 0.254829592f) * t;
  const float erf_abs = 1.0f - poly * __expf(-x * x);
  return 0.5f * v * (1.0f + copysignf(erf_abs, v));
}

// ---------------------------------------------------------------------------
// Kernel 1: group tokens by expert (single block). 128-tile map + 256-row
// supertile descriptors (two same-expert 128-tiles; odd leftover self-pairs).
// ---------------------------------------------------------------------------
__global__ void group_kernel(const int* __restrict__ eidx,
                             int* __restrict__ perm,
                             int* __restrict__ tile_e,
                             int* __restrict__ supA,
                             int* __restrict__ supB,
                             int* __restrict__ supE) {
  __shared__ int cnt[NE], off[NE], len[NE], cur[NE];
  const int tid = threadIdx.x;
  if (tid < NE) cnt[tid] = 0;
  __syncthreads();
  for (int i = tid; i < TOK; i += 256) atomicAdd(&cnt[eidx[i]], 1);
  __syncthreads();
  if (tid == 0) {
    int o = 0;
    for (int e = 0; e < NE; e++) {
      off[e] = o;
      len[e] = ((cnt[e] + BM - 1) / BM) * BM;
      cur[e] = o;
      o += len[e];
    }
    int ns = 0;
    for (int e = 0; e < NE; e++) {
      const int nt = len[e] / BM;
      for (int p = 0; p < nt; p += 2) {
        const int pb = (p + 1 < nt) ? (p + 1) : p;
        supA[ns] = off[e] + p * BM;
        supB[ns] = off[e] + pb * BM;
        supE[ns] = e;
        ns++;
      }
    }
    for (; ns < MAXSUP; ns++) { supA[ns] = 0; supB[ns] = 0; supE[ns] = -1; }
  }
  __syncthreads();
  for (int s = tid; s < PADMAX; s += 256) perm[s] = -1;
  __syncthreads();
  for (int i = tid; i < TOK; i += 256) {
    const int e = eidx[i];
    const int p = atomicAdd(&cur[e], 1);
    perm[p] = i;
  }
  __syncthreads();
  for (int t = tid; t < NTILES; t += 256) {
    const int row = t * BM;
    int te = -1;
    for (int e = 0; e < NE; e++)
      if (row >= off[e] && row < off[e] + len[e]) te = e;
    tile_e[t] = te;
  }
}

// ---------------------------------------------------------------------------
// convpack body (r9 proven): W [K][N] f32 -> WT [K/8][N][8] bf16.
// tid must be 0..255.
// ---------------------------------------------------------------------------
static __device__ __forceinline__
void convpack_body(const float* __restrict__ W, unsigned short* __restrict__ WT,
                   int K, int N, int kg, int nblk, int e, int tid) {
  const int n0 = nblk * 1024 + tid * 4;
  const float* Win = W + (size_t)e * K * N + (size_t)kg * 8 * N + n0;
  unsigned short* Wout = WT + (size_t)e * K * N + ((size_t)kg * N + n0) * 8;
  float4v v[8];
#pragma unroll
  for (int j = 0; j < 8; j++) v[j] = *(const float4v*)(Win + (size_t)j * N);
#pragma unroll
  for (int q = 0; q < 4; q++) {
    short8 g;
#pragma unroll
    for (int j = 0; j < 8; j++) g[j] = (short)f2bf(v[j][q]);
    *(short8*)(Wout + q * 8) = g;
  }
}

// ---------------------------------------------------------------------------
// Kernel 2 (prep1): convpack(W1) + xgather. (W2 conv is gemm1 tail work.)
// ---------------------------------------------------------------------------
__global__ __launch_bounds__(256)
void prep1_kernel(const float* __restrict__ W1, unsigned short* __restrict__ W1T,
                  const float* __restrict__ x, const int* __restrict__ perm,
                  unsigned short* __restrict__ xg) {
  const int bid = blockIdx.x;
  const int tid = threadIdx.x;
  if (bid < 4096) {
    convpack_body(W1, W1T, DIM, DMLP, bid & 127, (bid >> 7) & 3, bid >> 9, tid);
  } else {
    const int slot = bid - 4096;
    const int t    = perm[slot];
    ushort4v o = (ushort4v){0, 0, 0, 0};
    if (t >= 0) {
      const float4v v = *(const float4v*)(x + (size_t)t * DIM + tid * 4);
#pragma unroll
      for (int q = 0; q < 4; q++) o[q] = f2bf(v[q]);
    }
    *(ushort4v*)(xg + (size_t)slot * DIM + tid * 4) = o;
  }
}

// ---------------------------------------------------------------------------
// Kernel 3: h = gelu(xg @ W1 + b1), 8-PHASE 256x256 SCHEDULE (T3+T4+T5).
// 512 thr = 8 waves (2M x 4N), per-wave 128x64 out, BK=64, LDS 128 KB =
// 2 buf x {Ah0,Ah1,Bh0,Bh1}. Phase (mh,nh) computes C-quadrant mh,nh and
// consumes only A-half mh + B-half nh. Stage order Ah0,Bh0,Bh1,Ah1 (one
// half/phase); counted vmcnt(4) at p0/p1/p3 keeps >=2 half-tiles in flight
// through every MFMA cluster; no drain until loop end. setprio on MFMA.
// Rows 0-127 from supA, 128-255 from supB (same expert; self-pair benign).
// + W2 conv tail work. Grid: (DMLP/256=16, MAXSUP), 512 threads.
// ---------------------------------------------------------------------------
__global__ __launch_bounds__(512, 2)
void gemm1_kernel(const unsigned short* __restrict__ xg,
                  const unsigned short* __restrict__ W1T,
                  const float* __restrict__ b1,
                  const int* __restrict__ supA, const int* __restrict__ supB,
                  const int* __restrict__ supE,
                  unsigned short* __restrict__ h,
                  const float* __restrict__ W2, unsigned short* __restrict__ W2T) {
  const int s  = blockIdx.y;
  const int te = supE[s];
  const int n0 = blockIdx.x * 256;
  const int tid = threadIdx.x;

  // 128 KB. Buf b at b*32768 (shorts): Ah0@0 Ah1@8192 Bh0@16384 Bh1@24576.
  // Epilogue reuses all of it as the 256x256 bf16 C-tile.
  __shared__ __align__(16) unsigned short SMEM[65536];

  if (te >= 0) {
    const int rowA = supA[s], rowB = supB[s];
    const unsigned short* W1Te = W1T + (size_t)te * DIM * DMLP;

    // A staging map: load t2 in {0,1}: row = t2*64 + (tid>>3), granule col
    // swizzled c0 = (tid&7)^(r&7) (r&7 invariant under +64).
    const int r0 = tid >> 3;
    const int c0 = (tid & 7) ^ (r0 & 7);
    const unsigned short* aH0 = xg + (size_t)(rowA + r0) * DIM + c0 * 8;
    const unsigned short* aH1 = xg + (size_t)(rowB + r0) * DIM + c0 * 8;
    // B staging map: load t2: granule row C = t2*4 + (tid>>7), n = tid&127
    const unsigned short* bP = W1Te + ((size_t)(tid >> 7) * DMLP + n0 + (tid & 127)) * 8;

    const int wid = tid >> 6, lane = tid & 63;
    const int wr2 = wid >> 2;          // 0..1: 64-row strip within quadrant
    const int wc2 = wid & 3;           // 0..3: 32-col strip within quadrant
    const int l15 = lane & 15, quad = lane >> 4;

    float4v acc[2][4][2][2];           // [mh][mf][nh][nf]
#pragma unroll
    for (int a1 = 0; a1 < 2; a1++)
#pragma unroll
      for (int a2 = 0; a2 < 4; a2++)
#pragma unroll
        for (int a3 = 0; a3 < 2; a3++)
#pragma unroll
          for (int a4 = 0; a4 < 2; a4++)
            acc[a1][a2][a3][a4] = (float4v){0.f, 0.f, 0.f, 0.f};

#define SGA(nbuf, mh, tn) do {                                                 \
    const unsigned short* base_ = (mh) ? aH1 : aH0;                            \
    _Pragma("unroll")                                                          \
    for (int t2 = 0; t2 < 2; t2++)                                             \
      ASYNC16(base_ + (size_t)(t2 * 64) * DIM + (tn) * 64,                     \
              &SMEM[(nbuf) * 32768 + (mh) * 8192 + (t2 * 512 + tid) * 8]);     \
  } while (0)

#define SGB(nbuf, nh, tn) do {                                                 \
    _Pragma("unroll")                                                          \
    for (int t2 = 0; t2 < 2; t2++)                                             \
      ASYNC16(bP + ((size_t)((tn) * 8 + t2 * 4) * DMLP + (nh) * 128) * 8,      \
              &SMEM[(nbuf) * 32768 + 16384 + (nh) * 8192 +                     \
                    (t2 * 512 + tid) * 8]);                                    \
  } while (0)

#define PHASE(buf, MH, NH, STAGE_STMT, VM_STMT) do {                           \
    short8 a_[4][2], b_[2][2];                                                 \
    _Pragma("unroll")                                                          \
    for (int mf = 0; mf < 4; mf++)                                             \
      _Pragma("unroll")                                                        \
      for (int h2 = 0; h2 < 2; h2++)                                           \
        a_[mf][h2] = *(const short8*)&SMEM[(buf) * 32768 + (MH) * 8192 +       \
            FRAG_OFF64(wr2 * 64 + mf * 16 + l15, h2 * 4 + quad)];              \
    _Pragma("unroll")                                                          \
    for (int nf = 0; nf < 2; nf++)                                             \
      _Pragma("unroll")                                                        \
      for (int h2 = 0; h2 < 2; h2++)                                           \
        b_[nf][h2] = *(const short8*)&SMEM[(buf) * 32768 + 16384 +             \
            (NH) * 8192 +                                                      \
            ((((h2 * 4 + quad) << 7) + wc2 * 32 + nf * 16 + l15) << 3)];       \
    STAGE_STMT;                                                                \
    VM_STMT;                                                                   \
    __builtin_amdgcn_s_barrier();                                              \
    __builtin_amdgcn_sched_barrier(0);                                         \
    __builtin_amdgcn_s_setprio(1);                                             \
    _Pragma("unroll")                                                          \
    for (int mf = 0; mf < 4; mf++)                                             \
      _Pragma("unroll")                                                        \
      for (int nf = 0; nf < 2; nf++)                                           \
        _Pragma("unroll")                                                      \
        for (int h2 = 0; h2 < 2; h2++)                                         \
          acc[MH][mf][NH][nf] = __builtin_amdgcn_mfma_f32_16x16x32_bf16(       \
              a_[mf][h2], b_[nf][h2], acc[MH][mf][NH][nf], 0, 0, 0);           \
    __builtin_amdgcn_s_setprio(0);                                             \
    __builtin_amdgcn_sched_barrier(0);                                         \
    __builtin_amdgcn_s_barrier();                                              \
  } while (0)

#define VM4 asm volatile("s_waitcnt vmcnt(4)" ::: "memory")
#define VM2 asm volatile("s_waitcnt vmcnt(2)" ::: "memory")
#define VM0 asm volatile("s_waitcnt vmcnt(0)" ::: "memory")

    // prologue: stage tile 0 halves in order H0=Ah0,H1=Bh0,H2=Bh1,H3=Ah1
    SGA(0, 0, 0); SGB(0, 0, 0); SGB(0, 1, 0); SGA(0, 1, 0);
    VM4;                                  // H0,H1 landed (H2,H3 in flight)
    __builtin_amdgcn_s_barrier();
    __builtin_amdgcn_sched_barrier(0);

    for (int t = 0; t < NT1 - 1; ++t) {
      const int buf = t & 1, nbuf = buf ^ 1, tn = t + 1;
      PHASE(buf, 0, 0, SGA(nbuf, 0, tn), VM4);   // covers this tile's Bh1
      PHASE(buf, 0, 1, SGB(nbuf, 0, tn), VM4);   // covers this tile's Ah1
      PHASE(buf, 1, 0, SGB(nbuf, 1, tn), (void)0);
      PHASE(buf, 1, 1, SGA(nbuf, 1, tn), VM4);   // covers next tile's H0,H1
    }
    {
      const int buf = (NT1 - 1) & 1;
      PHASE(buf, 0, 0, (void)0, VM2);
      PHASE(buf, 0, 1, (void)0, VM0);
      PHASE(buf, 1, 0, (void)0, (void)0);
      PHASE(buf, 1, 1, (void)0, (void)0);
    }
#undef SGA
#undef SGB
#undef PHASE
#undef VM4
#undef VM2
#undef VM0

    // ---- epilogue: gelu -> bf16 into 256x256 LDS tile, then wide stores ----
    __syncthreads();                      // full fence before SMEM reuse
#pragma unroll
    for (int nh = 0; nh < 2; nh++) {
#pragma unroll
      for (int nf = 0; nf < 2; nf++) {
        const int col = nh * 128 + wc2 * 32 + nf * 16 + l15;
        const float bias = b1[te * DMLP + n0 + col];
#pragma unroll
        for (int mh = 0; mh < 2; mh++) {
#pragma unroll
          for (int mf = 0; mf < 4; mf++) {
#pragma unroll
            for (int r = 0; r < 4; r++) {
              const int row = mh * 128 + wr2 * 64 + mf * 16 + quad * 4 + r;
              SMEM[row * 256 + col] = f2bf(gelu_erf(acc[mh][mf][nh][nf][r] + bias));
            }
          }
        }
      }
    }
    __syncthreads();
#pragma unroll
    for (int rr = 0; rr < 16; rr++) {
      const int p = rr * 512 + tid;
      const int row = p >> 5, g = p & 31;
      const int grow = (row < 128) ? (rowA + row) : (rowB + row - 128);
      const ull2 v = *(const ull2*)&SMEM[row * 256 + g * 8];
      *(ull2*)&h[(size_t)grow * DMLP + n0 + g * 8] = v;
    }
  }

  // ---- tail: convert this block's share of W2 -> W2T (4096 chunks) -------
  const int fb = blockIdx.y * gridDim.x + blockIdx.x;   // 0..383
#pragma unroll
  for (int r = 0; r < 6; ++r) {
    const int c = fb * 2 + (tid >> 8) + 768 * r;
    if (c < 4096) convpack_body(W2, W2T, DMLP, DIM, c & 511, 0, c >> 9, tid & 255);
  }
}

// ---------------------------------------------------------------------------
// Kernel 4: out[tok] = h @ W2 + b2, scatter. 256x64 supertile, BK=128
// (r9 proven, untouched). Grid: (DIM/64, MAXSUP) col-fastest.
// ---------------------------------------------------------------------------
__global__ __launch_bounds__(256)
void gemm2_kernel(const unsigned short* __restrict__ h,
                  const unsigned short* __restrict__ W2T,
                  const float* __restrict__ b2, const int* __restrict__ perm,
                  const int* __restrict__ supA, const int* __restrict__ supB,
                  const int* __restrict__ supE, float* __restrict__ out) {
  const int s  = blockIdx.y;
  const int te = supE[s];
  if (te < 0) return;
  const int rowA = supA[s], rowB = supB[s];
  const int n0 = blockIdx.x * BN2;
  const int tid = threadIdx.x;

  __shared__ __align__(16) unsigned short As[256 * 128];    // 64 KB
  __shared__ __align__(16) unsigned short Bs[16 * BN2 * 8]; // 16 KB [C][64][8]

  const int rr = tid >> 4, q = tid & 15;
  const int cs = SWZ128(rr, q);
  const unsigned short* aA = h + (size_t)(rowA + rr) * DMLP + cs * 8;
  const unsigned short* aB = h + (size_t)(rowB + rr) * DMLP + cs * 8;
  const int bC = tid >> 6, bn = tid & 63;    // t adds 4 to C per step
  const unsigned short* b0 = W2T + (size_t)te * DMLP * DIM
                           + ((size_t)bC * DIM + n0 + bn) * 8;

  const int wid = tid >> 6, lane = tid & 63;
  const int wm = wid * 64;                   // 64 rows per wave
  const int l15 = lane & 15, quad = lane >> 4;

  float4v acc[4][4];
#pragma unroll
  for (int i = 0; i < 4; i++)
#pragma unroll
    for (int j = 0; j < 4; j++) acc[i][j] = (float4v){0.f, 0.f, 0.f, 0.f};

  for (int k0 = 0; k0 < DMLP; k0 += 128) {
    const int kg0 = k0 >> 3;
#pragma unroll
    for (int t = 0; t < 8; t++)
      ASYNC16(aA + (size_t)(16 * t) * DMLP + k0, &As[(t * 256 + tid) * 8]);
#pragma unroll
    for (int t = 0; t < 8; t++)
      ASYNC16(aB + (size_t)(16 * t) * DMLP + k0, &As[((t + 8) * 256 + tid) * 8]);
#pragma unroll
    for (int t = 0; t < 4; t++)
      ASYNC16(b0 + (size_t)(kg0 + 4 * t) * DIM * 8, &Bs[(t * 256 + tid) * 8]);
    __syncthreads();

#pragma unroll
    for (int hh = 0; hh < 4; hh++) {
      short8 a[4], b[4];
      const int C = hh * 4 + quad;
#pragma unroll
      for (int i = 0; i < 4; i++)
        a[i] = *(const short8*)&As[FRAG_OFF128(wm + i * 16 + l15, C)];
#pragma unroll
      for (int j = 0; j < 4; j++)
        b[j] = *(const short8*)&Bs[(((C) << 6) + j * 16 + l15) << 3];
#pragma unroll
      for (int i = 0; i < 4; i++)
#pragma unroll
        for (int j = 0; j < 4; j++)
          acc[i][j] = __builtin_amdgcn_mfma_f32_16x16x32_bf16(a[i], b[j], acc[i][j], 0, 0, 0);
    }
    __syncthreads();
  }

  const int halfbase = (wm < 128) ? (rowA + wm) : (rowB + (wm - 128));
#pragma unroll
  for (int i = 0; i < 4; i++) {
#pragma unroll
    for (int j = 0; j < 4; j++) {
      const int col = n0 + j * 16 + l15;
      const float bias = b2[te * DIM + col];
#pragma unroll
      for (int r = 0; r < 4; r++) {
        const int slot = halfbase + i * 16 + quad * 4 + r;
        const int t    = perm[slot];
        if (t >= 0) out[(size_t)t * DIM + col] = acc[i][j][r] + bias;
      }
    }
  }
}

// ---------------------------------------------------------------------------
extern "C" void kernel_launch(void* const* d_in, const int* in_sizes, int n_in,
                              void* d_out, int out_size, void* d_ws, size_t ws_size,
                              hipStream_t stream) {
  const float* x    = (const float*)d_in[0];
  const int*   eidx = (const int*)d_in[1];
  const float* W1   = (const float*)d_in[2];
  const float* b1   = (const float*)d_in[3];
  const float* W2   = (const float*)d_in[4];
  const float* b2   = (const float*)d_in[5];
  float* out = (float*)d_out;

  char* ws = (char*)d_ws;
  int* perm   = (int*)ws;                              // 5120 ints
  int* tile_e = (int*)(ws + PADMAX * sizeof(int));     // 40 ints
  int* supA   = (int*)(ws + 20736);                    // 24 ints
  int* supB   = (int*)(ws + 20832);                    // 24 ints
  int* supE   = (int*)(ws + 20928);                    // 24 ints
  unsigned short* xg  = (unsigned short*)(ws + 32768);                      // 10 MB
  unsigned short* h   = (unsigned short*)(ws + 32768 + 10485760);           // 40 MB
  unsigned short* W1T = (unsigned short*)(ws + 32768 + 10485760 + 41943040);// 64 MB
  unsigned short* W2T = (unsigned short*)((char*)W1T + 67108864);           // 64 MB

  group_kernel<<<1, 256, 0, stream>>>(eidx, perm, tile_e, supA, supB, supE);
  prep1_kernel<<<4096 + PADMAX, 256, 0, stream>>>(W1, W1T, x, perm, xg);
  gemm1_kernel<<<dim3(DMLP / 256, MAXSUP), 512, 0, stream>>>(xg, W1T, b1, supA, supB, supE, h, W2, W2T);
  gemm2_kernel<<<dim3(DIM / BN2, MAXSUP), 256, 0, stream>>>(h, W2T, b2, perm, supA, supB, supE, out);
}

// Round 14
// 454.442 us; speedup vs baseline: 1.1019x; 1.1019x over previous
//
#include <hip/hip_runtime.h>
#include <hip/hip_bf16.h>
#include <math.h>

#define TOK   4096
#define DIM   1024
#define DMLP  4096
#define NE    8
#define BM    128
#define BN    128
#define BN2   64
#define BK    128
#define PADMAX (TOK + NE * BM)   // 5120 padded slots
#define NTILES (PADMAX / BM)     // 40 row-tiles

typedef __attribute__((ext_vector_type(8))) short  short8;
typedef __attribute__((ext_vector_type(4))) float  float4v;
typedef __attribute__((ext_vector_type(4))) unsigned short ushort4v;
typedef __attribute__((ext_vector_type(2))) unsigned long long ull2;

// async global->LDS, 16 B per lane; LDS dest is wave-uniform base + lane*16
#define ASYNC16(gp, lp) __builtin_amdgcn_global_load_lds( \
    (const __attribute__((address_space(1))) unsigned int*)(gp), \
    (__attribute__((address_space(3))) unsigned int*)(lp), 16, 0, 0)

// A-side LDS layout (row-major, swizzled): BK=128 -> 16 granules/row
#define SWZ(R, C) (((C) & 8) | (((C) ^ (R)) & 7))
#define FRAG_OFF(R, C) ((((R) << 4) + SWZ(R, C)) << 3)
// B-side LDS layout (granule-major): [C][n][8], offset in shorts (n<128)
#define BOFF(C, n) ((((C) << 7) + (n)) << 3)

static __device__ __forceinline__ unsigned short f2bf(float f) {
  unsigned u = __float_as_uint(f);
  u += 0x7fffu + ((u >> 16) & 1u);
  return (unsigned short)(u >> 16);
}

// exact-erf GELU via Abramowitz&Stegun 7.1.26 (|err| < 1.5e-7)
static __device__ __forceinline__ float gelu_erf(float v) {
  const float x = fabsf(v) * 0.70710678118654752f;
  const float t = __builtin_amdgcn_rcpf(1.0f + 0.3275911f * x);
  const float poly = ((((1.061405429f * t - 1.453152027f) * t + 1.421413741f) * t
                       - 0.284496736f) * t + 0.254829592f) * t;
  const float erf_abs = 1.0f - poly * __expf(-x * x);
  return 0.5f * v * (1.0f + copysignf(erf_abs, v));
}

// ---------------------------------------------------------------------------
// Kernel 1: group tokens by expert (single block). 128-tile map.
// ---------------------------------------------------------------------------
__global__ void group_kernel(const int* __restrict__ eidx,
                             int* __restrict__ perm,
                             int* __restrict__ tile_e) {
  __shared__ int cnt[NE], off[NE], len[NE], cur[NE];
  const int tid = threadIdx.x;
  if (tid < NE) cnt[tid] = 0;
  __syncthreads();
  for (int i = tid; i < TOK; i += 256) atomicAdd(&cnt[eidx[i]], 1);
  __syncthreads();
  if (tid == 0) {
    int o = 0;
    for (int e = 0; e < NE; e++) {
      off[e] = o;
      len[e] = ((cnt[e] + BM - 1) / BM) * BM;
      cur[e] = o;
      o += len[e];
    }
  }
  __syncthreads();
  for (int s = tid; s < PADMAX; s += 256) perm[s] = -1;
  __syncthreads();
  for (int i = tid; i < TOK; i += 256) {
    const int e = eidx[i];
    const int p = atomicAdd(&cur[e], 1);
    perm[p] = i;
  }
  __syncthreads();
  for (int t = tid; t < NTILES; t += 256) {
    const int row = t * BM;
    int te = -1;
    for (int e = 0; e < NE; e++)
      if (row >= off[e] && row < off[e] + len[e]) te = e;
    tile_e[t] = te;
  }
}

// ---------------------------------------------------------------------------
// convpack body (r9 proven): W [K][N] f32 -> WT [K/8][N][8] bf16.
// float4 coalesced reads, fully contiguous 16 B/thread normal stores.
// ---------------------------------------------------------------------------
static __device__ __forceinline__
void convpack_body(const float* __restrict__ W, unsigned short* __restrict__ WT,
                   int K, int N, int kg, int nblk, int e, int tid) {
  const int n0 = nblk * 1024 + tid * 4;
  const float* Win = W + (size_t)e * K * N + (size_t)kg * 8 * N + n0;
  unsigned short* Wout = WT + (size_t)e * K * N + ((size_t)kg * N + n0) * 8;
  float4v v[8];
#pragma unroll
  for (int j = 0; j < 8; j++) v[j] = *(const float4v*)(Win + (size_t)j * N);
#pragma unroll
  for (int q = 0; q < 4; q++) {
    short8 g;
#pragma unroll
    for (int j = 0; j < 8; j++) g[j] = (short)f2bf(v[j][q]);
    *(short8*)(Wout + q * 8) = g;
  }
}

// ---------------------------------------------------------------------------
// Kernel 2 (prep1): convpack(W1) + xgather. (W2 conv is gemm1 tail work.)
// ---------------------------------------------------------------------------
__global__ __launch_bounds__(256)
void prep1_kernel(const float* __restrict__ W1, unsigned short* __restrict__ W1T,
                  const float* __restrict__ x, const int* __restrict__ perm,
                  unsigned short* __restrict__ xg) {
  const int bid = blockIdx.x;
  const int tid = threadIdx.x;
  if (bid < 4096) {
    convpack_body(W1, W1T, DIM, DMLP, bid & 127, (bid >> 7) & 3, bid >> 9, tid);
  } else {
    const int slot = bid - 4096;
    const int t    = perm[slot];
    ushort4v o = (ushort4v){0, 0, 0, 0};
    if (t >= 0) {
      const float4v v = *(const float4v*)(x + (size_t)t * DIM + tid * 4);
#pragma unroll
      for (int q = 0; q < 4; q++) o[q] = f2bf(v[q]);
    }
    *(ushort4v*)(xg + (size_t)slot * DIM + tid * 4) = o;
  }
}

// ---------------------------------------------------------------------------
// Kernel 3: h = gelu(xg @ W1 + b1) -> bf16. 128x128 tile, BK=128 (r11 exact,
// measured 105 us incl. tail). A: row-major swizzled; B: granule-major
// [C][128][8] staged from WT's [K/8][N][8] layout (1 KB contiguous source
// segments; 2-way-free LDS reads). + W2 conv tail work.
// Grid: (DMLP/BN, NTILES) col-fastest.
// ---------------------------------------------------------------------------
__global__ __launch_bounds__(256)
void gemm1_kernel(const unsigned short* __restrict__ xg,
                  const unsigned short* __restrict__ W1T,
                  const float* __restrict__ b1, const int* __restrict__ tile_e,
                  unsigned short* __restrict__ h,
                  const float* __restrict__ W2, unsigned short* __restrict__ W2T) {
  const int bt = blockIdx.y;                 // row tile
  const int te = tile_e[bt];
  const int n0 = blockIdx.x * BN;            // col tile
  const int tid = threadIdx.x;

  __shared__ __align__(16) unsigned short SMEM[2 * BM * BK];

  if (te >= 0) {
    const unsigned short* Asrc = xg + (size_t)bt * BM * DIM;
    const unsigned short* Bsrc = W1T + (size_t)te * DIM * DMLP + (size_t)n0 * 8;

    const int rr = tid >> 4, q = tid & 15;
    const int cs = SWZ(rr, q);
    const unsigned short* a0 = Asrc + (size_t)rr * DIM + cs * 8;
    const int bC = tid >> 7, bn = tid & 127;   // t adds 2 to C per step
    const unsigned short* b0 = Bsrc + ((size_t)bC * DMLP + bn) * 8;

    const int wid = tid >> 6, lane = tid & 63;
    const int wm = (wid >> 1) * 64, wn = (wid & 1) * 64;
    const int l15 = lane & 15, quad = lane >> 4;

    float4v acc[4][4];
#pragma unroll
    for (int i = 0; i < 4; i++)
#pragma unroll
      for (int j = 0; j < 4; j++) acc[i][j] = (float4v){0.f, 0.f, 0.f, 0.f};

    for (int k0 = 0; k0 < DIM; k0 += BK) {
      const int kg0 = k0 >> 3;
#pragma unroll
      for (int t = 0; t < 8; t++)
        ASYNC16(a0 + (size_t)(16 * t) * DIM + k0, &SMEM[(t * 256 + tid) * 8]);
#pragma unroll
      for (int t = 0; t < 8; t++)
        ASYNC16(b0 + (size_t)(kg0 + 2 * t) * DMLP * 8,
                &SMEM[BM * BK + (t * 256 + tid) * 8]);
      __syncthreads();

#pragma unroll
      for (int hh = 0; hh < 4; hh++) {
        short8 a[4], b[4];
        const int C = hh * 4 + quad;
#pragma unroll
        for (int i = 0; i < 4; i++)
          a[i] = *(const short8*)&SMEM[FRAG_OFF(wm + i * 16 + l15, C)];
#pragma unroll
        for (int j = 0; j < 4; j++)
          b[j] = *(const short8*)&SMEM[BM * BK + BOFF(C, wn + j * 16 + l15)];
#pragma unroll
        for (int i = 0; i < 4; i++)
#pragma unroll
          for (int j = 0; j < 4; j++)
            acc[i][j] = __builtin_amdgcn_mfma_f32_16x16x32_bf16(a[i], b[j], acc[i][j], 0, 0, 0);
      }
      __syncthreads();
    }

    // ---- epilogue: gelu -> bf16 into LDS tile, then coalesced wide stores --
#pragma unroll
    for (int i = 0; i < 4; i++) {
#pragma unroll
      for (int j = 0; j < 4; j++) {
        const int colL = wn + j * 16 + l15;
        const float bias = b1[te * DMLP + n0 + colL];
#pragma unroll
        for (int r = 0; r < 4; r++) {
          const int rowL = wm + i * 16 + quad * 4 + r;
          SMEM[rowL * BN + colL] = f2bf(gelu_erf(acc[i][j][r] + bias));
        }
      }
    }
    __syncthreads();
    const int gg = tid & 15;
    const int rb = tid >> 4;
#pragma unroll
    for (int p = 0; p < 8; p++) {
      const int rowL = rb + p * 16;
      const ull2 v = *(const ull2*)&SMEM[rowL * BN + gg * 8];
      *(ull2*)&h[(size_t)(bt * BM + rowL) * DMLP + n0 + gg * 8] = v;
    }
  }

  // ---- tail: convert this block's share of W2 -> W2T (4096 chunks) -------
  const int fb = bt * gridDim.x + blockIdx.x;   // flat block id, 0..1279
#pragma unroll
  for (int r = 0; r < 4; r++) {
    const int c = fb + 1280 * r;
    if (c < 4096) {
      convpack_body(W2, W2T, DMLP, DIM, c & 511, 0, c >> 9, tid);
    }
  }
}

// ---------------------------------------------------------------------------
// Kernel 4: out[tok] = h @ W2 + b2, scatter. 128x64 tile, BK=128 —
// r6's best-measured geometry (48 KB LDS -> 3 blocks/CU, 640 blocks, 81 us)
// combined with r9's granule-major B layout (kills r6's 7.3M bank conflicts).
// Grid: (DIM/64, NTILES) col-fastest.
// ---------------------------------------------------------------------------
__global__ __launch_bounds__(256)
void gemm2_kernel(const unsigned short* __restrict__ h,
                  const unsigned short* __restrict__ W2T,
                  const float* __restrict__ b2, const int* __restrict__ perm,
                  const int* __restrict__ tile_e, float* __restrict__ out) {
  const int bt = blockIdx.y;
  const int te = tile_e[bt];
  if (te < 0) return;
  const int n0 = blockIdx.x * BN2;
  const unsigned short* Asrc = h + (size_t)bt * BM * DMLP;
  const int tid = threadIdx.x;

  __shared__ __align__(16) unsigned short As[BM * BK];      // 32 KB
  __shared__ __align__(16) unsigned short Bs[16 * BN2 * 8]; // 16 KB [C][64][8]

  const int rr = tid >> 4, q = tid & 15;
  const int cs = SWZ(rr, q);
  const unsigned short* a0 = Asrc + (size_t)rr * DMLP + cs * 8;
  // B: granule p = t*256 + tid -> C = 4t + (tid>>6), n = tid&63
  const int bC = tid >> 6, bn = tid & 63;
  const unsigned short* b0 = W2T + (size_t)te * DMLP * DIM
                           + ((size_t)bC * DIM + n0 + bn) * 8;

  const int wid = tid >> 6, lane = tid & 63;
  const int wm = (wid >> 1) * 64, wn = (wid & 1) * 32;
  const int l15 = lane & 15, quad = lane >> 4;

  float4v acc[4][2];
#pragma unroll
  for (int i = 0; i < 4; i++)
#pragma unroll
    for (int j = 0; j < 2; j++) acc[i][j] = (float4v){0.f, 0.f, 0.f, 0.f};

  for (int k0 = 0; k0 < DMLP; k0 += BK) {
    const int kg0 = k0 >> 3;
#pragma unroll
    for (int t = 0; t < 8; t++)
      ASYNC16(a0 + (size_t)(16 * t) * DMLP + k0, &As[(t * 256 + tid) * 8]);
#pragma unroll
    for (int t = 0; t < 4; t++)
      ASYNC16(b0 + (size_t)(kg0 + 4 * t) * DIM * 8, &Bs[(t * 256 + tid) * 8]);
    __syncthreads();

#pragma unroll
    for (int hh = 0; hh < 4; hh++) {
      short8 a[4], b[2];
      const int C = hh * 4 + quad;
#pragma unroll
      for (int i = 0; i < 4; i++)
        a[i] = *(const short8*)&As[FRAG_OFF(wm + i * 16 + l15, C)];
#pragma unroll
      for (int j = 0; j < 2; j++)
        b[j] = *(const short8*)&Bs[(((C) << 6) + wn + j * 16 + l15) << 3];
#pragma unroll
      for (int i = 0; i < 4; i++)
#pragma unroll
        for (int j = 0; j < 2; j++)
          acc[i][j] = __builtin_amdgcn_mfma_f32_16x16x32_bf16(a[i], b[j], acc[i][j], 0, 0, 0);
    }
    __syncthreads();
  }

#pragma unroll
  for (int i = 0; i < 4; i++) {
#pragma unroll
    for (int j = 0; j < 2; j++) {
      const int col = n0 + wn + j * 16 + l15;
      const float bias = b2[te * DIM + col];
#pragma unroll
      for (int r = 0; r < 4; r++) {
        const int row  = wm + i * 16 + quad * 4 + r;
        const int slot = bt * BM + row;
        const int t    = perm[slot];
        if (t >= 0) out[(size_t)t * DIM + col] = acc[i][j][r] + bias;
      }
    }
  }
}

// ---------------------------------------------------------------------------
extern "C" void kernel_launch(void* const* d_in, const int* in_sizes, int n_in,
                              void* d_out, int out_size, void* d_ws, size_t ws_size,
                              hipStream_t stream) {
  const float* x    = (const float*)d_in[0];
  const int*   eidx = (const int*)d_in[1];
  const float* W1   = (const float*)d_in[2];
  const float* b1   = (const float*)d_in[3];
  const float* W2   = (const float*)d_in[4];
  const float* b2   = (const float*)d_in[5];
  float* out = (float*)d_out;

  char* ws = (char*)d_ws;
  int* perm   = (int*)ws;                              // 5120 ints
  int* tile_e = (int*)(ws + PADMAX * sizeof(int));     // 40 ints
  unsigned short* xg  = (unsigned short*)(ws + 32768);                      // 10 MB
  unsigned short* h   = (unsigned short*)(ws + 32768 + 10485760);           // 40 MB
  unsigned short* W1T = (unsigned short*)(ws + 32768 + 10485760 + 41943040);// 64 MB
  unsigned short* W2T = (unsigned short*)((char*)W1T + 67108864);           // 64 MB

  group_kernel<<<1, 256, 0, stream>>>(eidx, perm, tile_e);
  prep1_kernel<<<4096 + PADMAX, 256, 0, stream>>>(W1, W1T, x, perm, xg);
  gemm1_kernel<<<dim3(DMLP / BN, NTILES), 256, 0, stream>>>(xg, W1T, b1, tile_e, h, W2, W2T);
  gemm2_kernel<<<dim3(DIM / BN2, NTILES), 256, 0, stream>>>(h, W2T, b2, perm, tile_e, out);
}

// Round 15
// 445.782 us; speedup vs baseline: 1.1233x; 1.0194x over previous
//
#include <hip/hip_runtime.h>
#include <hip/hip_bf16.h>
#include <math.h>

#define TOK   4096
#define DIM   1024
#define DMLP  4096
#define NE    8
#define BM    128
#define BN    128
#define BN2   64
#define BK    128
#define PADMAX (TOK + NE * BM)   // 5120 padded slots
#define NTILES (PADMAX / BM)     // 40 row-tiles
#define EPAD  136                // epilogue LDS row stride (shorts), 16B-aligned

typedef __attribute__((ext_vector_type(8))) short  short8;
typedef __attribute__((ext_vector_type(4))) float  float4v;
typedef __attribute__((ext_vector_type(4))) unsigned short ushort4v;
typedef __attribute__((ext_vector_type(2))) unsigned long long ull2;

// async global->LDS, 16 B per lane; LDS dest is wave-uniform base + lane*16;
// GLOBAL source address is per-lane (enables the perm-gather A staging).
#define ASYNC16(gp, lp) __builtin_amdgcn_global_load_lds( \
    (const __attribute__((address_space(1))) unsigned int*)(gp), \
    (__attribute__((address_space(3))) unsigned int*)(lp), 16, 0, 0)

// A-side LDS layout (row-major, swizzled): BK=128 -> 16 granules/row
#define SWZ(R, C) (((C) & 8) | (((C) ^ (R)) & 7))
#define FRAG_OFF(R, C) ((((R) << 4) + SWZ(R, C)) << 3)
// B-side LDS layout (granule-major): [C][n][8], offset in shorts (n<128)
#define BOFF(C, n) ((((C) << 7) + (n)) << 3)

static __device__ __forceinline__ unsigned short f2bf(float f) {
  unsigned u = __float_as_uint(f);
  u += 0x7fffu + ((u >> 16) & 1u);
  return (unsigned short)(u >> 16);
}

// exact-erf GELU via Abramowitz&Stegun 7.1.26 (|err| < 1.5e-7)
static __device__ __forceinline__ float gelu_erf(float v) {
  const float x = fabsf(v) * 0.70710678118654752f;
  const float t = __builtin_amdgcn_rcpf(1.0f + 0.3275911f * x);
  const float poly = ((((1.061405429f * t - 1.453152027f) * t + 1.421413741f) * t
                       - 0.284496736f) * t + 0.254829592f) * t;
  const float erf_abs = 1.0f - poly * __expf(-x * x);
  return 0.5f * v * (1.0f + copysignf(erf_abs, v));
}

// ---------------------------------------------------------------------------
// group body (single block): token counts -> expert offsets -> perm/tile_e.
// ---------------------------------------------------------------------------
static __device__ __forceinline__
void group_body(const int* __restrict__ eidx, int* __restrict__ perm,
                int* __restrict__ tile_e, int tid) {
  __shared__ int cnt[NE], off[NE], len[NE], cur[NE];
  if (tid < NE) cnt[tid] = 0;
  __syncthreads();
  for (int i = tid; i < TOK; i += 256) atomicAdd(&cnt[eidx[i]], 1);
  __syncthreads();
  if (tid == 0) {
    int o = 0;
    for (int e = 0; e < NE; e++) {
      off[e] = o;
      len[e] = ((cnt[e] + BM - 1) / BM) * BM;
      cur[e] = o;
      o += len[e];
    }
  }
  __syncthreads();
  for (int s = tid; s < PADMAX; s += 256) perm[s] = -1;
  __syncthreads();
  for (int i = tid; i < TOK; i += 256) {
    const int e = eidx[i];
    const int p = atomicAdd(&cur[e], 1);
    perm[p] = i;
  }
  __syncthreads();
  for (int t = tid; t < NTILES; t += 256) {
    const int row = t * BM;
    int te = -1;
    for (int e = 0; e < NE; e++)
      if (row >= off[e] && row < off[e] + len[e]) te = e;
    tile_e[t] = te;
  }
}

// ---------------------------------------------------------------------------
// convpack body (r9 proven): W [K][N] f32 -> WT [K/8][N][8] bf16.
// ---------------------------------------------------------------------------
static __device__ __forceinline__
void convpack_body(const float* __restrict__ W, unsigned short* __restrict__ WT,
                   int K, int N, int kg, int nblk, int e, int tid) {
  const int n0 = nblk * 1024 + tid * 4;
  const float* Win = W + (size_t)e * K * N + (size_t)kg * 8 * N + n0;
  unsigned short* Wout = WT + (size_t)e * K * N + ((size_t)kg * N + n0) * 8;
  float4v v[8];
#pragma unroll
  for (int j = 0; j < 8; j++) v[j] = *(const float4v*)(Win + (size_t)j * N);
#pragma unroll
  for (int q = 0; q < 4; q++) {
    short8 g;
#pragma unroll
    for (int j = 0; j < 8; j++) g[j] = (short)f2bf(v[j][q]);
    *(short8*)(Wout + q * 8) = g;
  }
}

// ---------------------------------------------------------------------------
// Kernel 1 (prep): group (block 0) + convpack(W1) + x f32->bf16 TOKEN-ORDER.
// No intra-kernel dependencies: perm/tile_e are consumed only by the next
// launch; x-convert needs no perm (gemm1 gathers via per-lane ASYNC16 src).
// Blocks: [0]=group, [1,4097)=W1 conv, [4097,8193)=x rows.
// ---------------------------------------------------------------------------
__global__ __launch_bounds__(256)
void prep_kernel(const int* __restrict__ eidx, int* __restrict__ perm,
                 int* __restrict__ tile_e,
                 const float* __restrict__ W1, unsigned short* __restrict__ W1T,
                 const float* __restrict__ x, unsigned short* __restrict__ xbf) {
  const int bid = blockIdx.x;
  const int tid = threadIdx.x;
  if (bid == 0) {
    group_body(eidx, perm, tile_e, tid);
  } else if (bid < 4097) {
    const int b = bid - 1;
    convpack_body(W1, W1T, DIM, DMLP, b & 127, (b >> 7) & 3, b >> 9, tid);
  } else {
    const int row = bid - 4097;           // 0..4095, token order
    const float4v v = *(const float4v*)(x + (size_t)row * DIM + tid * 4);
    ushort4v o;
#pragma unroll
    for (int q = 0; q < 4; q++) o[q] = f2bf(v[q]);
    *(ushort4v*)(xbf + (size_t)row * DIM + tid * 4) = o;
  }
}

// ---------------------------------------------------------------------------
// Kernel 2: h = gelu(x[perm] @ W1 + b1) -> bf16. 128x128 tile, BK=128.
// A staged DIRECTLY from token-ordered xbf via per-lane perm-gathered global
// addresses (deletes the xgather pass). B granule-major (r9). Epilogue LDS
// restage padded to stride 136 (kills the 3.0M stride-128 bank conflicts).
// + W2 conv tail work. Grid: (DMLP/BN, NTILES) col-fastest.
// ---------------------------------------------------------------------------
__global__ __launch_bounds__(256)
void gemm1_kernel(const unsigned short* __restrict__ xbf,
                  const unsigned short* __restrict__ W1T,
                  const float* __restrict__ b1, const int* __restrict__ perm,
                  const int* __restrict__ tile_e,
                  unsigned short* __restrict__ h,
                  const float* __restrict__ W2, unsigned short* __restrict__ W2T) {
  const int bt = blockIdx.y;                 // row tile
  const int te = tile_e[bt];
  const int n0 = blockIdx.x * BN;            // col tile
  const int tid = threadIdx.x;

  __shared__ __align__(16) unsigned short SMEM[2 * BM * BK];

  if (te >= 0) {
    const unsigned short* Bsrc = W1T + (size_t)te * DIM * DMLP + (size_t)n0 * 8;

    const int rr = tid >> 4, q = tid & 15;
    const int cs = SWZ(rr, q);
    // per-row gathered A sources: staged row at load t is 16t + rr
    const unsigned short* aP[8];
#pragma unroll
    for (int t = 0; t < 8; t++) {
      const int tok = perm[bt * BM + 16 * t + rr];
      aP[t] = xbf + (size_t)(tok < 0 ? 0 : tok) * DIM + cs * 8;
    }
    const int bC = tid >> 7, bn = tid & 127;   // t adds 2 to C per step
    const unsigned short* b0 = Bsrc + ((size_t)bC * DMLP + bn) * 8;

    const int wid = tid >> 6, lane = tid & 63;
    const int wm = (wid >> 1) * 64, wn = (wid & 1) * 64;
    const int l15 = lane & 15, quad = lane >> 4;

    float4v acc[4][4];
#pragma unroll
    for (int i = 0; i < 4; i++)
#pragma unroll
      for (int j = 0; j < 4; j++) acc[i][j] = (float4v){0.f, 0.f, 0.f, 0.f};

    for (int k0 = 0; k0 < DIM; k0 += BK) {
      const int kg0 = k0 >> 3;
#pragma unroll
      for (int t = 0; t < 8; t++)
        ASYNC16(aP[t] + k0, &SMEM[(t * 256 + tid) * 8]);
#pragma unroll
      for (int t = 0; t < 8; t++)
        ASYNC16(b0 + (size_t)(kg0 + 2 * t) * DMLP * 8,
                &SMEM[BM * BK + (t * 256 + tid) * 8]);
      __syncthreads();

#pragma unroll
      for (int hh = 0; hh < 4; hh++) {
        short8 a[4], b[4];
        const int C = hh * 4 + quad;
#pragma unroll
        for (int i = 0; i < 4; i++)
          a[i] = *(const short8*)&SMEM[FRAG_OFF(wm + i * 16 + l15, C)];
#pragma unroll
        for (int j = 0; j < 4; j++)
          b[j] = *(const short8*)&SMEM[BM * BK + BOFF(C, wn + j * 16 + l15)];
#pragma unroll
        for (int i = 0; i < 4; i++)
#pragma unroll
          for (int j = 0; j < 4; j++)
            acc[i][j] = __builtin_amdgcn_mfma_f32_16x16x32_bf16(a[i], b[j], acc[i][j], 0, 0, 0);
      }
      __syncthreads();
    }

    // ---- epilogue: gelu -> bf16 into padded LDS tile, then wide stores ----
#pragma unroll
    for (int i = 0; i < 4; i++) {
#pragma unroll
      for (int j = 0; j < 4; j++) {
        const int colL = wn + j * 16 + l15;
        const float bias = b1[te * DMLP + n0 + colL];
#pragma unroll
        for (int r = 0; r < 4; r++) {
          const int rowL = wm + i * 16 + quad * 4 + r;
          SMEM[rowL * EPAD + colL] = f2bf(gelu_erf(acc[i][j][r] + bias));
        }
      }
    }
    __syncthreads();
    const int gg = tid & 15;
    const int rb = tid >> 4;
#pragma unroll
    for (int p = 0; p < 8; p++) {
      const int rowL = rb + p * 16;
      const ull2 v = *(const ull2*)&SMEM[rowL * EPAD + gg * 8];
      *(ull2*)&h[(size_t)(bt * BM + rowL) * DMLP + n0 + gg * 8] = v;
    }
  }

  // ---- tail: convert this block's share of W2 -> W2T (4096 chunks) -------
  const int fb = bt * gridDim.x + blockIdx.x;   // flat block id, 0..1279
#pragma unroll
  for (int r = 0; r < 4; r++) {
    const int c = fb + 1280 * r;
    if (c < 4096) {
      convpack_body(W2, W2T, DMLP, DIM, c & 511, 0, c >> 9, tid);
    }
  }
}

// ---------------------------------------------------------------------------
// Kernel 3: out[tok] = h @ W2 + b2, scatter. 128x64 tile, BK=128 (r14 exact:
// 48 KB LDS -> 3 blocks/CU, 640 blocks, granule-major B, conflict-free).
// Grid: (DIM/64, NTILES) col-fastest.
// ---------------------------------------------------------------------------
__global__ __launch_bounds__(256)
void gemm2_kernel(const unsigned short* __restrict__ h,
                  const unsigned short* __restrict__ W2T,
                  const float* __restrict__ b2, const int* __restrict__ perm,
                  const int* __restrict__ tile_e, float* __restrict__ out) {
  const int bt = blockIdx.y;
  const int te = tile_e[bt];
  if (te < 0) return;
  const int n0 = blockIdx.x * BN2;
  const unsigned short* Asrc = h + (size_t)bt * BM * DMLP;
  const int tid = threadIdx.x;

  __shared__ __align__(16) unsigned short As[BM * BK];      // 32 KB
  __shared__ __align__(16) unsigned short Bs[16 * BN2 * 8]; // 16 KB [C][64][8]

  const int rr = tid >> 4, q = tid & 15;
  const int cs = SWZ(rr, q);
  const unsigned short* a0 = Asrc + (size_t)rr * DMLP + cs * 8;
  const int bC = tid >> 6, bn = tid & 63;
  const unsigned short* b0 = W2T + (size_t)te * DMLP * DIM
                           + ((size_t)bC * DIM + n0 + bn) * 8;

  const int wid = tid >> 6, lane = tid & 63;
  const int wm = (wid >> 1) * 64, wn = (wid & 1) * 32;
  const int l15 = lane & 15, quad = lane >> 4;

  float4v acc[4][2];
#pragma unroll
  for (int i = 0; i < 4; i++)
#pragma unroll
    for (int j = 0; j < 2; j++) acc[i][j] = (float4v){0.f, 0.f, 0.f, 0.f};

  for (int k0 = 0; k0 < DMLP; k0 += BK) {
    const int kg0 = k0 >> 3;
#pragma unroll
    for (int t = 0; t < 8; t++)
      ASYNC16(a0 + (size_t)(16 * t) * DMLP + k0, &As[(t * 256 + tid) * 8]);
#pragma unroll
    for (int t = 0; t < 4; t++)
      ASYNC16(b0 + (size_t)(kg0 + 4 * t) * DIM * 8, &Bs[(t * 256 + tid) * 8]);
    __syncthreads();

#pragma unroll
    for (int hh = 0; hh < 4; hh++) {
      short8 a[4], b[2];
      const int C = hh * 4 + quad;
#pragma unroll
      for (int i = 0; i < 4; i++)
        a[i] = *(const short8*)&As[FRAG_OFF(wm + i * 16 + l15, C)];
#pragma unroll
      for (int j = 0; j < 2; j++)
        b[j] = *(const short8*)&Bs[(((C) << 6) + wn + j * 16 + l15) << 3];
#pragma unroll
      for (int i = 0; i < 4; i++)
#pragma unroll
        for (int j = 0; j < 2; j++)
          acc[i][j] = __builtin_amdgcn_mfma_f32_16x16x32_bf16(a[i], b[j], acc[i][j], 0, 0, 0);
    }
    __syncthreads();
  }

#pragma unroll
  for (int i = 0; i < 4; i++) {
#pragma unroll
    for (int j = 0; j < 2; j++) {
      const int col = n0 + wn + j * 16 + l15;
      const float bias = b2[te * DIM + col];
#pragma unroll
      for (int r = 0; r < 4; r++) {
        const int row  = wm + i * 16 + quad * 4 + r;
        const int slot = bt * BM + row;
        const int t    = perm[slot];
        if (t >= 0) out[(size_t)t * DIM + col] = acc[i][j][r] + bias;
      }
    }
  }
}

// ---------------------------------------------------------------------------
extern "C" void kernel_launch(void* const* d_in, const int* in_sizes, int n_in,
                              void* d_out, int out_size, void* d_ws, size_t ws_size,
                              hipStream_t stream) {
  const float* x    = (const float*)d_in[0];
  const int*   eidx = (const int*)d_in[1];
  const float* W1   = (const float*)d_in[2];
  const float* b1   = (const float*)d_in[3];
  const float* W2   = (const float*)d_in[4];
  const float* b2   = (const float*)d_in[5];
  float* out = (float*)d_out;

  char* ws = (char*)d_ws;
  int* perm   = (int*)ws;                              // 5120 ints
  int* tile_e = (int*)(ws + PADMAX * sizeof(int));     // 40 ints
  unsigned short* xbf = (unsigned short*)(ws + 32768);                      // 8 MB
  unsigned short* h   = (unsigned short*)(ws + 32768 + 10485760);           // 40 MB
  unsigned short* W1T = (unsigned short*)(ws + 32768 + 10485760 + 41943040);// 64 MB
  unsigned short* W2T = (unsigned short*)((char*)W1T + 67108864);           // 64 MB

  prep_kernel<<<8193, 256, 0, stream>>>(eidx, perm, tile_e, W1, W1T, x, xbf);
  gemm1_kernel<<<dim3(DMLP / BN, NTILES), 256, 0, stream>>>(xbf, W1T, b1, perm, tile_e, h, W2, W2T);
  gemm2_kernel<<<dim3(DIM / BN2, NTILES), 256, 0, stream>>>(h, W2T, b2, perm, tile_e, out);
}